// Round 4
// baseline (934.473 us; speedup 1.0000x reference)
//
#include <hip/hip_runtime.h>
#include <stdint.h>

#define S_TOK 8192
#define HID 2880
#define NQ 64
#define NKV 8
#define HD 64
#define QKV_N 5120   // 4096 q + 512 k + 512 v
#define NO_PAD 2944  // 2880 padded to multiple of 128

typedef __attribute__((ext_vector_type(8))) __bf16 bf16x8;
typedef __attribute__((ext_vector_type(4))) float f32x4;

__device__ __forceinline__ unsigned short f2bf(float f) {
  unsigned int u = __builtin_bit_cast(unsigned int, f);
  u += 0x7fff + ((u >> 16) & 1);
  return (unsigned short)(u >> 16);
}
__device__ __forceinline__ float bf2f(unsigned short h) {
  unsigned int u = ((unsigned int)h) << 16;
  return __builtin_bit_cast(float, u);
}

__device__ __forceinline__ void async_lds16(const void* g, void* l) {
  __builtin_amdgcn_global_load_lds(
      (const __attribute__((address_space(1))) unsigned int*)g,
      (__attribute__((address_space(3))) unsigned int*)l, 16, 0, 0);
}

__device__ __forceinline__ void wg_barrier() {
  asm volatile("" ::: "memory");
  __builtin_amdgcn_s_barrier();
  asm volatile("" ::: "memory");
}

#define VMCNT(n) asm volatile("s_waitcnt vmcnt(" #n ")" ::: "memory")
#define LGKM0                                            \
  do {                                                   \
    asm volatile("s_waitcnt lgkmcnt(0)" ::: "memory");   \
    __builtin_amdgcn_sched_barrier(0);                   \
  } while (0)

// ---------------- elementwise f32 -> bf16 ----------------
__global__ __launch_bounds__(256) void cvt_bf16_kernel(
    const float* __restrict__ src, unsigned short* __restrict__ dst) {
  size_t i = ((size_t)blockIdx.x * 256 + threadIdx.x) * 8;
  float4 a = *(const float4*)(src + i);
  float4 b = *(const float4*)(src + i + 4);
  union { unsigned short u[8]; uint4 v; } o;
  o.u[0] = f2bf(a.x); o.u[1] = f2bf(a.y); o.u[2] = f2bf(a.z); o.u[3] = f2bf(a.w);
  o.u[4] = f2bf(b.x); o.u[5] = f2bf(b.y); o.u[6] = f2bf(b.z); o.u[7] = f2bf(b.w);
  *(uint4*)(dst + i) = o.v;
}

// ------------- transpose + convert: src[R][C] f32 -> dst[(c+rowOff)][R] bf16 -------------
__global__ __launch_bounds__(256) void transpose_cvt(
    const float* __restrict__ src, unsigned short* __restrict__ dst,
    int R, int C, int rowOff) {
  __shared__ float tile[32][33];
  int tx = threadIdx.x, ty = threadIdx.y;  // block (32,8)
  int c0 = blockIdx.x * 32, r0 = blockIdx.y * 32;
#pragma unroll
  for (int i = 0; i < 4; ++i)
    tile[ty + i * 8][tx] = src[(size_t)(r0 + ty + i * 8) * C + c0 + tx];
  __syncthreads();
#pragma unroll
  for (int i = 0; i < 4; ++i)
    dst[(size_t)(c0 + ty + i * 8 + rowOff) * R + r0 + tx] = f2bf(tile[tx][ty + i * 8]);
}

// ---------------- in-place RoPE on q (heads 0..63) and k (heads 64..71) ----------------
__global__ __launch_bounds__(256) void rope_kernel(
    unsigned short* __restrict__ qkv, const int* __restrict__ positions) {
  int gid = blockIdx.x * 256 + threadIdx.x;   // 8192*72*32 total
  int d = gid & 31;
  int rest = gid >> 5;
  int head = rest % 72;
  int t = rest / 72;
  unsigned short* p = qkv + (size_t)t * QKV_N + head * 64;
  float x1 = bf2f(p[d]);
  float x2 = bf2f(p[d + 32]);
  float pos = (float)positions[t];
  float inv = exp2f(-0.5373313430f * (float)d);
  float ang = pos * inv;
  float s = sinf(ang), c = cosf(ang);
  p[d] = f2bf(x1 * c - x2 * s);
  p[d + 32] = f2bf(x2 * c + x1 * s);
}

// ======================= 256x256 4-phase bf16 GEMM (m201-geometry) =======================
// 8 waves (2M x 4N), per-wave 128x64 C (acc = 8m x 4n x f32x4), 16x16x32 MFMA.
// MFMA:ds_read = 64:24 per wave per K-tile -- critical path on MFMA, not LDS-read.
// LDS 128KB: 2 dbuf x {A[2 kh][256 x 32], B[2 kh][256 x 32]} ushorts; each K-half is a
// separate contiguous 16KB region so global_load_lds dest stays lane-linear (16B/lane).
// Swizzle: stored chunk c holds global chunk c ^ ((row>>1)&3); read chunk
// l4 ^ ((l15>>1)&3) yields global chunk l4 (the MFMA fragment K-offset).
// Half-granular producer-consumer in the double buffer (unit = 1 stage call = 2 loads):
//   p0 (ks0,mh0): stage A_k1(t+1)->buf^1 | reads B_k0+A_k0
//   p1 (ks0,mh1): stage B_k0(t+2)->buf   | reads A_k0
//   p2 (ks1,mh0): stage A_k0(t+2)->buf   | reads B_k1+A_k1
//   p3 (ks1,mh1): stage B_k1(t+2)->buf   | reads A_k1
// Every stage-issue follows the barrier after its region's last consuming read.
// Counted gates: vmcnt(10) at p0/p2 steady state (tail: 4 / 8 / 0) -- never drain
// mid-loop (T4). Ledger: at p0, needed units are #6-7 from newest (<=10 loads pending
// covers the 5 newest units); at p2, needed unit is #6 from newest.
template <int MODE>
__global__ __launch_bounds__(512, 2) void gemm256(
    const unsigned short* __restrict__ A, const unsigned short* __restrict__ BT,
    void* __restrict__ Cout, int K, int NT, int nbClamp, int gx,
    const float* __restrict__ b0, const float* __restrict__ b1,
    const float* __restrict__ b2) {
  __shared__ unsigned short lds[65536];  // 128 KB
  const int tid = threadIdx.x;
  const int lane = tid & 63;
  const int wid = tid >> 6;
  const int wy = wid >> 2, wx = wid & 3;       // 2M x 4N wave grid
  const int l15 = lane & 15, l4 = lane >> 4;
  const int psw = l4 ^ ((l15 >> 1) & 3);       // thread-constant read swizzle chunk

  // XCD-aware bijective swizzle (grid % 8 == 0 in both modes)
  int nwg = gridDim.x;
  int bid = blockIdx.x;
  int swz = (bid & 7) * (nwg >> 3) + (bid >> 3);
  int bx = swz % gx, by = swz / gx;
  const int m0 = by * 256, n0 = bx * 256;

  const unsigned short* Ag = A + (size_t)m0 * K;

  // staging: thread-constant source chunk + row
  const int row0 = tid >> 2;
  const int gsw = (tid & 3) ^ ((tid >> 3) & 3);

  auto stageA = [&](int t, int kh, int buf) {
    const unsigned short* G = Ag + t * 64 + kh * 32;
    unsigned short* D = &lds[buf * 32768 + kh * 8192];
#pragma unroll
    for (int rd = 0; rd < 2; ++rd) {
      int row = row0 + rd * 128;
      async_lds16(G + (size_t)row * K + gsw * 8, D + (tid + rd * 512) * 8);
    }
  };
  auto stageB = [&](int t, int kh, int buf) {
    int koff = t * 64 + kh * 32;
    unsigned short* D = &lds[buf * 32768 + 16384 + kh * 8192];
#pragma unroll
    for (int rd = 0; rd < 2; ++rd) {
      int gr = n0 + row0 + rd * 128;
      gr = gr > nbClamp ? nbClamp : gr;
      async_lds16(BT + (size_t)gr * K + koff + gsw * 8, D + (tid + rd * 512) * 8);
    }
  };

  f32x4 acc[8][4];
#pragma unroll
  for (int m = 0; m < 8; ++m)
#pragma unroll
    for (int n = 0; n < 4; ++n)
#pragma unroll
      for (int r = 0; r < 4; ++r) acc[m][n][r] = 0.f;

  // prologue ledger (issue order == steady state):
  // B_k0(0) A_k0(0) B_k1(0) A_k1(0) B_k0(1) A_k0(1) B_k1(1)   [A_k1(1) at t=0 p0]
  stageB(0, 0, 0); stageA(0, 0, 0); stageB(0, 1, 0); stageA(0, 1, 0);
  stageB(1, 0, 1); stageA(1, 0, 1); stageB(1, 1, 1);

  bf16x8 aq[4], bq[4];
  for (int t = 0; t < NT; ++t) {
    const int cur = t & 1;
    const unsigned short* Ab0 = &lds[cur * 32768];
    const unsigned short* Bb0 = Ab0 + 16384;
    const unsigned short* Ab1 = Ab0 + 8192;
    const unsigned short* Bb1 = Bb0 + 8192;

    // ---- p0: ks0, mh0 ----
    if (t + 1 < NT) { VMCNT(10); } else { VMCNT(4); }
    wg_barrier();
    if (t + 1 < NT) stageA(t + 1, 1, cur ^ 1);
#pragma unroll
    for (int n = 0; n < 4; ++n)
      bq[n] = *(const bf16x8*)&Bb0[(wx * 64 + n * 16 + l15) * 32 + psw * 8];
#pragma unroll
    for (int mi = 0; mi < 4; ++mi)
      aq[mi] = *(const bf16x8*)&Ab0[(wy * 128 + mi * 16 + l15) * 32 + psw * 8];
    LGKM0;
    __builtin_amdgcn_s_setprio(1);
#pragma unroll
    for (int mi = 0; mi < 4; ++mi)
#pragma unroll
      for (int n = 0; n < 4; ++n)
        acc[mi][n] = __builtin_amdgcn_mfma_f32_16x16x32_bf16(
            aq[mi], bq[n], acc[mi][n], 0, 0, 0);
    __builtin_amdgcn_s_setprio(0);

    // ---- p1: ks0, mh1 ----
    wg_barrier();
    if (t + 2 < NT) stageB(t + 2, 0, cur);
#pragma unroll
    for (int mi = 0; mi < 4; ++mi)
      aq[mi] = *(const bf16x8*)&Ab0[(wy * 128 + (mi + 4) * 16 + l15) * 32 + psw * 8];
    LGKM0;
    __builtin_amdgcn_s_setprio(1);
#pragma unroll
    for (int mi = 0; mi < 4; ++mi)
#pragma unroll
      for (int n = 0; n < 4; ++n)
        acc[mi + 4][n] = __builtin_amdgcn_mfma_f32_16x16x32_bf16(
            aq[mi], bq[n], acc[mi + 4][n], 0, 0, 0);
    __builtin_amdgcn_s_setprio(0);

    // ---- p2: ks1, mh0 ----
    if (t + 2 < NT) { VMCNT(10); }
    else if (t + 1 < NT) { VMCNT(8); }
    else { VMCNT(0); }
    wg_barrier();
    if (t + 2 < NT) stageA(t + 2, 0, cur);
#pragma unroll
    for (int n = 0; n < 4; ++n)
      bq[n] = *(const bf16x8*)&Bb1[(wx * 64 + n * 16 + l15) * 32 + psw * 8];
#pragma unroll
    for (int mi = 0; mi < 4; ++mi)
      aq[mi] = *(const bf16x8*)&Ab1[(wy * 128 + mi * 16 + l15) * 32 + psw * 8];
    LGKM0;
    __builtin_amdgcn_s_setprio(1);
#pragma unroll
    for (int mi = 0; mi < 4; ++mi)
#pragma unroll
      for (int n = 0; n < 4; ++n)
        acc[mi][n] = __builtin_amdgcn_mfma_f32_16x16x32_bf16(
            aq[mi], bq[n], acc[mi][n], 0, 0, 0);
    __builtin_amdgcn_s_setprio(0);

    // ---- p3: ks1, mh1 ----
    wg_barrier();
    if (t + 2 < NT) stageB(t + 2, 1, cur);
#pragma unroll
    for (int mi = 0; mi < 4; ++mi)
      aq[mi] = *(const bf16x8*)&Ab1[(wy * 128 + (mi + 4) * 16 + l15) * 32 + psw * 8];
    LGKM0;
    __builtin_amdgcn_s_setprio(1);
#pragma unroll
    for (int mi = 0; mi < 4; ++mi)
#pragma unroll
      for (int n = 0; n < 4; ++n)
        acc[mi + 4][n] = __builtin_amdgcn_mfma_f32_16x16x32_bf16(
            aq[mi], bq[n], acc[mi + 4][n], 0, 0, 0);
    __builtin_amdgcn_s_setprio(0);
  }
  __syncthreads();

  // C/D layout (16x16): col = lane&15, row = (lane>>4)*4 + reg
  if (MODE == 0) {
    unsigned short* C16 = (unsigned short*)Cout;
    unsigned short* ldsC = lds;  // 128 rows x 264 stride per half
#pragma unroll
    for (int h = 0; h < 2; ++h) {
      if (wy == h) {
#pragma unroll
        for (int n = 0; n < 4; ++n) {
          int col = wx * 64 + n * 16 + l15;
          int gcol = n0 + col;
          float bias = (gcol < 4096) ? b0[gcol]
                                     : (gcol < 4608 ? b1[gcol - 4096] : b2[gcol - 4608]);
#pragma unroll
          for (int m = 0; m < 8; ++m)
#pragma unroll
            for (int r = 0; r < 4; ++r)
              ldsC[(m * 16 + l4 * 4 + r) * 264 + col] = f2bf(acc[m][n][r] + bias);
        }
      }
      __syncthreads();
#pragma unroll
      for (int it = 0; it < 8; ++it) {  // 128 x 256 = 8 * 512 * 8
        int s = tid + it * 512;
        int row = s >> 5, c8 = (s & 31) * 8;
        *(uint4*)(C16 + (size_t)(m0 + h * 128 + row) * QKV_N + n0 + c8) =
            *(const uint4*)&ldsC[row * 264 + c8];
      }
      if (h == 0) __syncthreads();
    }
  } else {
    float* Cf = (float*)Cout;
#pragma unroll
    for (int n = 0; n < 4; ++n) {
      int gcol = n0 + wx * 64 + n * 16 + l15;
      if (gcol < HID) {
        float bias = b0[gcol];
#pragma unroll
        for (int m = 0; m < 8; ++m)
#pragma unroll
          for (int r = 0; r < 4; ++r) {
            int row = m0 + wy * 128 + m * 16 + l4 * 4 + r;
            Cf[(size_t)row * HID + gcol] = acc[m][n][r] + bias;
          }
      }
    }
  }
}

// ---------------- sliding-window GQA attention ----------------
// grid (128 q-blocks of 64 rows, 64 heads); block 256
__global__ __launch_bounds__(256) void attn_kernel(
    const unsigned short* __restrict__ qkv, unsigned short* __restrict__ attn) {
  __shared__ unsigned short Qs[64 * 72];    // q rows, stride 72 (pad)
  __shared__ unsigned short Ks[192 * 72];   // ctx keys, stride 72; reused as P[64*200]
  __shared__ unsigned short VTs[64 * 200];  // V transposed: [dim][key], stride 200

  const int tid = threadIdx.x;
  const int B = blockIdx.x;   // 64-row query block
  const int h = blockIdx.y;
  const int hk = h >> 3;
  const int wave = tid >> 6, lane = tid & 63;
  const int quad = lane >> 4, ml = lane & 15;

  // stage Q: 64 rows x 64 cols
#pragma unroll
  for (int it = 0; it < 2; ++it) {
    int s = tid + it * 256;
    int row = s >> 3, c = (s & 7) << 3;
    *(uint4*)&Qs[row * 72 + c] =
        *(const uint4*)(qkv + (size_t)(B * 64 + row) * QKV_N + h * 64 + c);
  }
  // stage K (natural) and V (transposed): 192 ctx rows
#pragma unroll
  for (int it = 0; it < 6; ++it) {
    int s = tid + it * 256;
    int j = s >> 3, c = (s & 7) << 3;
    int tk = B * 64 - 128 + j;
    uint4 kv = make_uint4(0, 0, 0, 0), vv = make_uint4(0, 0, 0, 0);
    if (tk >= 0) {
      kv = *(const uint4*)(qkv + (size_t)tk * QKV_N + 4096 + hk * 64 + c);
      vv = *(const uint4*)(qkv + (size_t)tk * QKV_N + 4608 + hk * 64 + c);
    }
    *(uint4*)&Ks[j * 72 + c] = kv;
    union { uint4 q; unsigned short u[8]; } vu;
    vu.q = vv;
#pragma unroll
    for (int e = 0; e < 8; ++e) VTs[(c + e) * 200 + j] = vu.u[e];
  }
  __syncthreads();

  // scores: wave handles q rows [wave*16, wave*16+16), all 192 ctx cols
  f32x4 zero = {0.f, 0.f, 0.f, 0.f};
  f32x4 sc[12];
#pragma unroll
  for (int jn = 0; jn < 12; ++jn) sc[jn] = zero;
#pragma unroll
  for (int kk = 0; kk < 2; ++kk) {
    bf16x8 af = *(const bf16x8*)&Qs[(wave * 16 + ml) * 72 + kk * 32 + quad * 8];
#pragma unroll
    for (int jn = 0; jn < 12; ++jn) {
      bf16x8 bfr = *(const bf16x8*)&Ks[(jn * 16 + ml) * 72 + kk * 32 + quad * 8];
      sc[jn] = __builtin_amdgcn_mfma_f32_16x16x32_bf16(af, bfr, sc[jn], 0, 0, 0);
    }
  }

  // mask + scale + softmax (rows = wave*16 + quad*4 + r; col = jn*16 + ml)
  const float NEG = -3.0e38f;
  float mx[4], sm[4];
#pragma unroll
  for (int r = 0; r < 4; ++r) mx[r] = NEG;
#pragma unroll
  for (int jn = 0; jn < 12; ++jn) {
    int j = jn * 16 + ml;
#pragma unroll
    for (int r = 0; r < 4; ++r) {
      int i = wave * 16 + quad * 4 + r;
      bool valid = (j > i) && (j <= i + 128) && (B * 64 + j - 128 >= 0);
      float v = valid ? sc[jn][r] * 0.125f : NEG;
      sc[jn][r] = v;
      mx[r] = fmaxf(mx[r], v);
    }
  }
#pragma unroll
  for (int r = 0; r < 4; ++r) {
#pragma unroll
    for (int off = 1; off < 16; off <<= 1)
      mx[r] = fmaxf(mx[r], __shfl_xor(mx[r], off, 64));
    sm[r] = 0.f;
  }
#pragma unroll
  for (int jn = 0; jn < 12; ++jn) {
#pragma unroll
    for (int r = 0; r < 4; ++r) {
      float p = expf(sc[jn][r] - mx[r]);  // masked entries underflow to 0
      sc[jn][r] = p;
      sm[r] += p;
    }
  }
#pragma unroll
  for (int r = 0; r < 4; ++r) {
#pragma unroll
    for (int off = 1; off < 16; off <<= 1) sm[r] += __shfl_xor(sm[r], off, 64);
    sm[r] = 1.0f / sm[r];
  }
  __syncthreads();  // everyone done reading Qs/Ks before P overwrites Ks

  unsigned short* P = Ks;  // overlay: 64 rows, stride 200
#pragma unroll
  for (int jn = 0; jn < 12; ++jn) {
#pragma unroll
    for (int r = 0; r < 4; ++r)
      P[(wave * 16 + quad * 4 + r) * 200 + jn * 16 + ml] = f2bf(sc[jn][r] * sm[r]);
  }
  __syncthreads();

  // PV: O[16 x 64] per wave, K-dim = 192
  f32x4 ov[4];
#pragma unroll
  for (int jn = 0; jn < 4; ++jn) ov[jn] = zero;
#pragma unroll
  for (int ks = 0; ks < 6; ++ks) {
    bf16x8 af = *(const bf16x8*)&P[(wave * 16 + ml) * 200 + ks * 32 + quad * 8];
#pragma unroll
    for (int jn = 0; jn < 4; ++jn) {
      bf16x8 bfr = *(const bf16x8*)&VTs[(jn * 16 + ml) * 200 + ks * 32 + quad * 8];
      ov[jn] = __builtin_amdgcn_mfma_f32_16x16x32_bf16(af, bfr, ov[jn], 0, 0, 0);
    }
  }
#pragma unroll
  for (int jn = 0; jn < 4; ++jn) {
#pragma unroll
    for (int r = 0; r < 4; ++r) {
      int row = B * 64 + wave * 16 + quad * 4 + r;
      attn[(size_t)row * 4096 + h * 64 + jn * 16 + ml] = f2bf(ov[jn][r]);
    }
  }
}

extern "C" void kernel_launch(void* const* d_in, const int* in_sizes, int n_in,
                              void* d_out, int out_size, void* d_ws, size_t ws_size,
                              hipStream_t stream) {
  const float* hidden = (const float*)d_in[0];
  const int* positions = (const int*)d_in[1];
  const float* Wq = (const float*)d_in[2];
  const float* bq = (const float*)d_in[3];
  const float* Wk = (const float*)d_in[4];
  const float* bk = (const float*)d_in[5];
  const float* Wv = (const float*)d_in[6];
  const float* bv = (const float*)d_in[7];
  const float* Wo = (const float*)d_in[8];
  const float* bo = (const float*)d_in[9];
  float* out = (float*)d_out;

  char* ws = (char*)d_ws;
  unsigned short* A_h   = (unsigned short*)(ws);
  unsigned short* BTqkv = (unsigned short*)(ws + 47185920);
  unsigned short* qkv   = (unsigned short*)(ws + 76677120);
  unsigned short* BTo   = (unsigned short*)(ws + 160563200);
  unsigned short* attn  = (unsigned short*)(ws);

  cvt_bf16_kernel<<<11520, 256, 0, stream>>>(hidden, A_h);
  dim3 tb(32, 8);
  transpose_cvt<<<dim3(128, 90), tb, 0, stream>>>(Wq, BTqkv, HID, 4096, 0);
  transpose_cvt<<<dim3(16, 90), tb, 0, stream>>>(Wk, BTqkv, HID, 512, 4096);
  transpose_cvt<<<dim3(16, 90), tb, 0, stream>>>(Wv, BTqkv, HID, 512, 4608);
  transpose_cvt<<<dim3(90, 128), tb, 0, stream>>>(Wo, BTo, 4096, HID, 0);
  hipMemsetAsync(BTo + (size_t)HID * 4096, 0, (size_t)(NO_PAD - HID) * 4096 * 2, stream);

  // mode-0: M=8192, N=5120 (20 col-blocks), K=2880 (NT=45); grid 640 (%8==0)
  gemm256<0><<<dim3(20 * 32), 512, 0, stream>>>(
      A_h, BTqkv, qkv, HID, 45, QKV_N - 1, 20, bq, bk, bv);
  rope_kernel<<<73728, 256, 0, stream>>>(qkv, positions);
  attn_kernel<<<dim3(S_TOK / 64, NQ), 256, 0, stream>>>(qkv, attn);
  // mode-1: N=2944 -> 12 col-blocks of 256 (B rows clamped to 2943, zeros), K=4096 (NT=64)
  gemm256<1><<<dim3(12 * 32), 512, 0, stream>>>(
      attn, BTo, out, 4096, 64, NO_PAD - 1, 12, bo, nullptr, nullptr);
}

// Round 5
// 924.486 us; speedup vs baseline: 1.0108x; 1.0108x over previous
//
#include <hip/hip_runtime.h>
#include <stdint.h>

#define S_TOK 8192
#define HID 2880
#define NQ 64
#define NKV 8
#define HD 64
#define QKV_N 5120   // 4096 q + 512 k + 512 v
#define NO_PAD 2944  // 2880 padded to multiple of 128

typedef __attribute__((ext_vector_type(8))) __bf16 bf16x8;
typedef __attribute__((ext_vector_type(4))) float f32x4;

__device__ __forceinline__ unsigned short f2bf(float f) {
  unsigned int u = __builtin_bit_cast(unsigned int, f);
  u += 0x7fff + ((u >> 16) & 1);
  return (unsigned short)(u >> 16);
}
__device__ __forceinline__ float bf2f(unsigned short h) {
  unsigned int u = ((unsigned int)h) << 16;
  return __builtin_bit_cast(float, u);
}

__device__ __forceinline__ void async_lds16(const void* g, void* l) {
  __builtin_amdgcn_global_load_lds(
      (const __attribute__((address_space(1))) unsigned int*)g,
      (__attribute__((address_space(3))) unsigned int*)l, 16, 0, 0);
}

__device__ __forceinline__ void wg_barrier() {
  asm volatile("" ::: "memory");
  __builtin_amdgcn_s_barrier();
  asm volatile("" ::: "memory");
}

#define VMCNT(n) asm volatile("s_waitcnt vmcnt(" #n ")" ::: "memory")
#define LGKM0                                            \
  do {                                                   \
    asm volatile("s_waitcnt lgkmcnt(0)" ::: "memory");   \
    __builtin_amdgcn_sched_barrier(0);                   \
  } while (0)

// ---------------- elementwise f32 -> bf16 ----------------
__global__ __launch_bounds__(256) void cvt_bf16_kernel(
    const float* __restrict__ src, unsigned short* __restrict__ dst) {
  size_t i = ((size_t)blockIdx.x * 256 + threadIdx.x) * 8;
  float4 a = *(const float4*)(src + i);
  float4 b = *(const float4*)(src + i + 4);
  union { unsigned short u[8]; uint4 v; } o;
  o.u[0] = f2bf(a.x); o.u[1] = f2bf(a.y); o.u[2] = f2bf(a.z); o.u[3] = f2bf(a.w);
  o.u[4] = f2bf(b.x); o.u[5] = f2bf(b.y); o.u[6] = f2bf(b.z); o.u[7] = f2bf(b.w);
  *(uint4*)(dst + i) = o.v;
}

// ------------- transpose + convert: src[R][C] f32 -> dst[(c+rowOff)][R] bf16 -------------
__global__ __launch_bounds__(256) void transpose_cvt(
    const float* __restrict__ src, unsigned short* __restrict__ dst,
    int R, int C, int rowOff) {
  __shared__ float tile[32][33];
  int tx = threadIdx.x, ty = threadIdx.y;  // block (32,8)
  int c0 = blockIdx.x * 32, r0 = blockIdx.y * 32;
#pragma unroll
  for (int i = 0; i < 4; ++i)
    tile[ty + i * 8][tx] = src[(size_t)(r0 + ty + i * 8) * C + c0 + tx];
  __syncthreads();
#pragma unroll
  for (int i = 0; i < 4; ++i)
    dst[(size_t)(c0 + ty + i * 8 + rowOff) * R + r0 + tx] = f2bf(tile[tx][ty + i * 8]);
}

// ---------------- in-place RoPE on q (heads 0..63) and k (heads 64..71) ----------------
__global__ __launch_bounds__(256) void rope_kernel(
    unsigned short* __restrict__ qkv, const int* __restrict__ positions) {
  int gid = blockIdx.x * 256 + threadIdx.x;   // 8192*72*32 total
  int d = gid & 31;
  int rest = gid >> 5;
  int head = rest % 72;
  int t = rest / 72;
  unsigned short* p = qkv + (size_t)t * QKV_N + head * 64;
  float x1 = bf2f(p[d]);
  float x2 = bf2f(p[d + 32]);
  float pos = (float)positions[t];
  float inv = exp2f(-0.5373313430f * (float)d);
  float ang = pos * inv;
  float s = sinf(ang), c = cosf(ang);
  p[d] = f2bf(x1 * c - x2 * s);
  p[d + 32] = f2bf(x2 * c + x1 * s);
}

// ======================= 256x256 4-phase bf16 GEMM (m201-geometry) =======================
// Schedule/ledger identical to the round-4 passing kernel. NEW: XCD 4x4 block clustering.
//
// Round-4 counters: MfmaUtil 36%, FETCH 358MB (ideal 77), bank-conflict 0. Diagnosis:
// L2-level demand = 640blk x 45tile x 64KB = 1.84GB -> 18 TB/s at MFMA-bound speed;
// delivered 6.4 TB/s because each XCD's 32 concurrent blocks spanned ~33MB of panels
// (vs 4MB L2) -> B-panel reads missed L2 and saturated the L3/IF fabric.
//
// Fix: HW dispatches blockIdx round-robin over 8 XCDs (bid&7). Map each XCD's blocks
// to 4x4 rects in (by,bx): concurrent working set per XCD = 2 rects x (4 A + 4 B)
// K-slices x 2-tile lookahead ~= 1MB -> L2-resident; K-lockstep blocks turn the 8x
// intra-rect amplification into L2 hits. RPX = rects per XCD, RCOLS = rect columns.
// mode-0: 640 = 8 xcd x 5 rects (RCOLS=5); mode-1: 384 = 8 x 3 (RCOLS=3).
template <int MODE>
__global__ __launch_bounds__(512, 2) void gemm256(
    const unsigned short* __restrict__ A, const unsigned short* __restrict__ BT,
    void* __restrict__ Cout, int K, int NT, int nbClamp, int RPX, int RCOLS,
    const float* __restrict__ b0, const float* __restrict__ b1,
    const float* __restrict__ b2) {
  __shared__ unsigned short lds[65536];  // 128 KB
  const int tid = threadIdx.x;
  const int lane = tid & 63;
  const int wid = tid >> 6;
  const int wy = wid >> 2, wx = wid & 3;       // 2M x 4N wave grid
  const int l15 = lane & 15, l4 = lane >> 4;
  const int psw = l4 ^ ((l15 >> 1) & 3);       // thread-constant read swizzle chunk

  // XCD 4x4 cluster mapping (bijective: (xcd,s) -> (r,w) -> (by,bx))
  const int bid = blockIdx.x;
  const int xcd = bid & 7, s = bid >> 3;
  const int r = xcd * RPX + (s >> 4);
  const int w = s & 15;
  const int by = (r / RCOLS) * 4 + (w >> 2);
  const int bx = (r % RCOLS) * 4 + (w & 3);
  const int m0 = by * 256, n0 = bx * 256;

  const unsigned short* Ag = A + (size_t)m0 * K;

  // staging: thread-constant source chunk + row
  const int row0 = tid >> 2;
  const int gsw = (tid & 3) ^ ((tid >> 3) & 3);

  auto stageA = [&](int t, int kh, int buf) {
    const unsigned short* G = Ag + t * 64 + kh * 32;
    unsigned short* D = &lds[buf * 32768 + kh * 8192];
#pragma unroll
    for (int rd = 0; rd < 2; ++rd) {
      int row = row0 + rd * 128;
      async_lds16(G + (size_t)row * K + gsw * 8, D + (tid + rd * 512) * 8);
    }
  };
  auto stageB = [&](int t, int kh, int buf) {
    int koff = t * 64 + kh * 32;
    unsigned short* D = &lds[buf * 32768 + 16384 + kh * 8192];
#pragma unroll
    for (int rd = 0; rd < 2; ++rd) {
      int gr = n0 + row0 + rd * 128;
      gr = gr > nbClamp ? nbClamp : gr;
      async_lds16(BT + (size_t)gr * K + koff + gsw * 8, D + (tid + rd * 512) * 8);
    }
  };

  f32x4 acc[8][4];
#pragma unroll
  for (int m = 0; m < 8; ++m)
#pragma unroll
    for (int n = 0; n < 4; ++n)
#pragma unroll
      for (int r2 = 0; r2 < 4; ++r2) acc[m][n][r2] = 0.f;

  // prologue ledger (issue order == steady state):
  // B_k0(0) A_k0(0) B_k1(0) A_k1(0) B_k0(1) A_k0(1) B_k1(1)   [A_k1(1) at t=0 p0]
  stageB(0, 0, 0); stageA(0, 0, 0); stageB(0, 1, 0); stageA(0, 1, 0);
  stageB(1, 0, 1); stageA(1, 0, 1); stageB(1, 1, 1);

  bf16x8 aq[4], bq[4];
  for (int t = 0; t < NT; ++t) {
    const int cur = t & 1;
    const unsigned short* Ab0 = &lds[cur * 32768];
    const unsigned short* Bb0 = Ab0 + 16384;
    const unsigned short* Ab1 = Ab0 + 8192;
    const unsigned short* Bb1 = Bb0 + 8192;

    // ---- p0: ks0, mh0 ----
    if (t + 1 < NT) { VMCNT(10); } else { VMCNT(4); }
    wg_barrier();
    if (t + 1 < NT) stageA(t + 1, 1, cur ^ 1);
#pragma unroll
    for (int n = 0; n < 4; ++n)
      bq[n] = *(const bf16x8*)&Bb0[(wx * 64 + n * 16 + l15) * 32 + psw * 8];
#pragma unroll
    for (int mi = 0; mi < 4; ++mi)
      aq[mi] = *(const bf16x8*)&Ab0[(wy * 128 + mi * 16 + l15) * 32 + psw * 8];
    LGKM0;
    __builtin_amdgcn_s_setprio(1);
#pragma unroll
    for (int mi = 0; mi < 4; ++mi)
#pragma unroll
      for (int n = 0; n < 4; ++n)
        acc[mi][n] = __builtin_amdgcn_mfma_f32_16x16x32_bf16(
            aq[mi], bq[n], acc[mi][n], 0, 0, 0);
    __builtin_amdgcn_s_setprio(0);

    // ---- p1: ks0, mh1 ----
    wg_barrier();
    if (t + 2 < NT) stageB(t + 2, 0, cur);
#pragma unroll
    for (int mi = 0; mi < 4; ++mi)
      aq[mi] = *(const bf16x8*)&Ab0[(wy * 128 + (mi + 4) * 16 + l15) * 32 + psw * 8];
    LGKM0;
    __builtin_amdgcn_s_setprio(1);
#pragma unroll
    for (int mi = 0; mi < 4; ++mi)
#pragma unroll
      for (int n = 0; n < 4; ++n)
        acc[mi + 4][n] = __builtin_amdgcn_mfma_f32_16x16x32_bf16(
            aq[mi], bq[n], acc[mi + 4][n], 0, 0, 0);
    __builtin_amdgcn_s_setprio(0);

    // ---- p2: ks1, mh0 ----
    if (t + 2 < NT) { VMCNT(10); }
    else if (t + 1 < NT) { VMCNT(8); }
    else { VMCNT(0); }
    wg_barrier();
    if (t + 2 < NT) stageA(t + 2, 0, cur);
#pragma unroll
    for (int n = 0; n < 4; ++n)
      bq[n] = *(const bf16x8*)&Bb1[(wx * 64 + n * 16 + l15) * 32 + psw * 8];
#pragma unroll
    for (int mi = 0; mi < 4; ++mi)
      aq[mi] = *(const bf16x8*)&Ab1[(wy * 128 + mi * 16 + l15) * 32 + psw * 8];
    LGKM0;
    __builtin_amdgcn_s_setprio(1);
#pragma unroll
    for (int mi = 0; mi < 4; ++mi)
#pragma unroll
      for (int n = 0; n < 4; ++n)
        acc[mi][n] = __builtin_amdgcn_mfma_f32_16x16x32_bf16(
            aq[mi], bq[n], acc[mi][n], 0, 0, 0);
    __builtin_amdgcn_s_setprio(0);

    // ---- p3: ks1, mh1 ----
    wg_barrier();
    if (t + 2 < NT) stageB(t + 2, 1, cur);
#pragma unroll
    for (int mi = 0; mi < 4; ++mi)
      aq[mi] = *(const bf16x8*)&Ab1[(wy * 128 + (mi + 4) * 16 + l15) * 32 + psw * 8];
    LGKM0;
    __builtin_amdgcn_s_setprio(1);
#pragma unroll
    for (int mi = 0; mi < 4; ++mi)
#pragma unroll
      for (int n = 0; n < 4; ++n)
        acc[mi + 4][n] = __builtin_amdgcn_mfma_f32_16x16x32_bf16(
            aq[mi], bq[n], acc[mi + 4][n], 0, 0, 0);
    __builtin_amdgcn_s_setprio(0);
  }
  __syncthreads();

  // C/D layout (16x16): col = lane&15, row = (lane>>4)*4 + reg
  if (MODE == 0) {
    unsigned short* C16 = (unsigned short*)Cout;
    unsigned short* ldsC = lds;  // 128 rows x 264 stride per half
#pragma unroll
    for (int h = 0; h < 2; ++h) {
      if (wy == h) {
#pragma unroll
        for (int n = 0; n < 4; ++n) {
          int col = wx * 64 + n * 16 + l15;
          int gcol = n0 + col;
          float bias = (gcol < 4096) ? b0[gcol]
                                     : (gcol < 4608 ? b1[gcol - 4096] : b2[gcol - 4608]);
#pragma unroll
          for (int m = 0; m < 8; ++m)
#pragma unroll
            for (int r2 = 0; r2 < 4; ++r2)
              ldsC[(m * 16 + l4 * 4 + r2) * 264 + col] = f2bf(acc[m][n][r2] + bias);
        }
      }
      __syncthreads();
#pragma unroll
      for (int it = 0; it < 8; ++it) {  // 128 x 256 = 8 * 512 * 8
        int s2 = tid + it * 512;
        int row = s2 >> 5, c8 = (s2 & 31) * 8;
        *(uint4*)(C16 + (size_t)(m0 + h * 128 + row) * QKV_N + n0 + c8) =
            *(const uint4*)&ldsC[row * 264 + c8];
      }
      if (h == 0) __syncthreads();
    }
  } else {
    float* Cf = (float*)Cout;
#pragma unroll
    for (int n = 0; n < 4; ++n) {
      int gcol = n0 + wx * 64 + n * 16 + l15;
      if (gcol < HID) {
        float bias = b0[gcol];
#pragma unroll
        for (int m = 0; m < 8; ++m)
#pragma unroll
          for (int r2 = 0; r2 < 4; ++r2) {
            int row = m0 + wy * 128 + m * 16 + l4 * 4 + r2;
            Cf[(size_t)row * HID + gcol] = acc[m][n][r2] + bias;
          }
      }
    }
  }
}

// ---------------- sliding-window GQA attention ----------------
// grid (128 q-blocks of 64 rows, 64 heads); block 256
__global__ __launch_bounds__(256) void attn_kernel(
    const unsigned short* __restrict__ qkv, unsigned short* __restrict__ attn) {
  __shared__ unsigned short Qs[64 * 72];    // q rows, stride 72 (pad)
  __shared__ unsigned short Ks[192 * 72];   // ctx keys, stride 72; reused as P[64*200]
  __shared__ unsigned short VTs[64 * 200];  // V transposed: [dim][key], stride 200

  const int tid = threadIdx.x;
  const int B = blockIdx.x;   // 64-row query block
  const int h = blockIdx.y;
  const int hk = h >> 3;
  const int wave = tid >> 6, lane = tid & 63;
  const int quad = lane >> 4, ml = lane & 15;

  // stage Q: 64 rows x 64 cols
#pragma unroll
  for (int it = 0; it < 2; ++it) {
    int s = tid + it * 256;
    int row = s >> 3, c = (s & 7) << 3;
    *(uint4*)&Qs[row * 72 + c] =
        *(const uint4*)(qkv + (size_t)(B * 64 + row) * QKV_N + h * 64 + c);
  }
  // stage K (natural) and V (transposed): 192 ctx rows
#pragma unroll
  for (int it = 0; it < 6; ++it) {
    int s = tid + it * 256;
    int j = s >> 3, c = (s & 7) << 3;
    int tk = B * 64 - 128 + j;
    uint4 kv = make_uint4(0, 0, 0, 0), vv = make_uint4(0, 0, 0, 0);
    if (tk >= 0) {
      kv = *(const uint4*)(qkv + (size_t)tk * QKV_N + 4096 + hk * 64 + c);
      vv = *(const uint4*)(qkv + (size_t)tk * QKV_N + 4608 + hk * 64 + c);
    }
    *(uint4*)&Ks[j * 72 + c] = kv;
    union { uint4 q; unsigned short u[8]; } vu;
    vu.q = vv;
#pragma unroll
    for (int e = 0; e < 8; ++e) VTs[(c + e) * 200 + j] = vu.u[e];
  }
  __syncthreads();

  // scores: wave handles q rows [wave*16, wave*16+16), all 192 ctx cols
  f32x4 zero = {0.f, 0.f, 0.f, 0.f};
  f32x4 sc[12];
#pragma unroll
  for (int jn = 0; jn < 12; ++jn) sc[jn] = zero;
#pragma unroll
  for (int kk = 0; kk < 2; ++kk) {
    bf16x8 af = *(const bf16x8*)&Qs[(wave * 16 + ml) * 72 + kk * 32 + quad * 8];
#pragma unroll
    for (int jn = 0; jn < 12; ++jn) {
      bf16x8 bfr = *(const bf16x8*)&Ks[(jn * 16 + ml) * 72 + kk * 32 + quad * 8];
      sc[jn] = __builtin_amdgcn_mfma_f32_16x16x32_bf16(af, bfr, sc[jn], 0, 0, 0);
    }
  }

  // mask + scale + softmax (rows = wave*16 + quad*4 + r; col = jn*16 + ml)
  const float NEG = -3.0e38f;
  float mx[4], sm[4];
#pragma unroll
  for (int r = 0; r < 4; ++r) mx[r] = NEG;
#pragma unroll
  for (int jn = 0; jn < 12; ++jn) {
    int j = jn * 16 + ml;
#pragma unroll
    for (int r = 0; r < 4; ++r) {
      int i = wave * 16 + quad * 4 + r;
      bool valid = (j > i) && (j <= i + 128) && (B * 64 + j - 128 >= 0);
      float v = valid ? sc[jn][r] * 0.125f : NEG;
      sc[jn][r] = v;
      mx[r] = fmaxf(mx[r], v);
    }
  }
#pragma unroll
  for (int r = 0; r < 4; ++r) {
#pragma unroll
    for (int off = 1; off < 16; off <<= 1)
      mx[r] = fmaxf(mx[r], __shfl_xor(mx[r], off, 64));
    sm[r] = 0.f;
  }
#pragma unroll
  for (int jn = 0; jn < 12; ++jn) {
#pragma unroll
    for (int r = 0; r < 4; ++r) {
      float p = expf(sc[jn][r] - mx[r]);  // masked entries underflow to 0
      sc[jn][r] = p;
      sm[r] += p;
    }
  }
#pragma unroll
  for (int r = 0; r < 4; ++r) {
#pragma unroll
    for (int off = 1; off < 16; off <<= 1) sm[r] += __shfl_xor(sm[r], off, 64);
    sm[r] = 1.0f / sm[r];
  }
  __syncthreads();  // everyone done reading Qs/Ks before P overwrites Ks

  unsigned short* P = Ks;  // overlay: 64 rows, stride 200
#pragma unroll
  for (int jn = 0; jn < 12; ++jn) {
#pragma unroll
    for (int r = 0; r < 4; ++r)
      P[(wave * 16 + quad * 4 + r) * 200 + jn * 16 + ml] = f2bf(sc[jn][r] * sm[r]);
  }
  __syncthreads();

  // PV: O[16 x 64] per wave, K-dim = 192
  f32x4 ov[4];
#pragma unroll
  for (int jn = 0; jn < 4; ++jn) ov[jn] = zero;
#pragma unroll
  for (int ks = 0; ks < 6; ++ks) {
    bf16x8 af = *(const bf16x8*)&P[(wave * 16 + ml) * 200 + ks * 32 + quad * 8];
#pragma unroll
    for (int jn = 0; jn < 4; ++jn) {
      bf16x8 bfr = *(const bf16x8*)&VTs[(jn * 16 + ml) * 200 + ks * 32 + quad * 8];
      ov[jn] = __builtin_amdgcn_mfma_f32_16x16x32_bf16(af, bfr, ov[jn], 0, 0, 0);
    }
  }
#pragma unroll
  for (int jn = 0; jn < 4; ++jn) {
#pragma unroll
    for (int r = 0; r < 4; ++r) {
      int row = B * 64 + wave * 16 + quad * 4 + r;
      attn[(size_t)row * 4096 + h * 64 + jn * 16 + ml] = f2bf(ov[jn][r]);
    }
  }
}

extern "C" void kernel_launch(void* const* d_in, const int* in_sizes, int n_in,
                              void* d_out, int out_size, void* d_ws, size_t ws_size,
                              hipStream_t stream) {
  const float* hidden = (const float*)d_in[0];
  const int* positions = (const int*)d_in[1];
  const float* Wq = (const float*)d_in[2];
  const float* bq = (const float*)d_in[3];
  const float* Wk = (const float*)d_in[4];
  const float* bk = (const float*)d_in[5];
  const float* Wv = (const float*)d_in[6];
  const float* bv = (const float*)d_in[7];
  const float* Wo = (const float*)d_in[8];
  const float* bo = (const float*)d_in[9];
  float* out = (float*)d_out;

  char* ws = (char*)d_ws;
  unsigned short* A_h   = (unsigned short*)(ws);
  unsigned short* BTqkv = (unsigned short*)(ws + 47185920);
  unsigned short* qkv   = (unsigned short*)(ws + 76677120);
  unsigned short* BTo   = (unsigned short*)(ws + 160563200);
  unsigned short* attn  = (unsigned short*)(ws);

  cvt_bf16_kernel<<<11520, 256, 0, stream>>>(hidden, A_h);
  dim3 tb(32, 8);
  transpose_cvt<<<dim3(128, 90), tb, 0, stream>>>(Wq, BTqkv, HID, 4096, 0);
  transpose_cvt<<<dim3(16, 90), tb, 0, stream>>>(Wk, BTqkv, HID, 512, 4096);
  transpose_cvt<<<dim3(16, 90), tb, 0, stream>>>(Wv, BTqkv, HID, 512, 4608);
  transpose_cvt<<<dim3(90, 128), tb, 0, stream>>>(Wo, BTo, 4096, HID, 0);
  hipMemsetAsync(BTo + (size_t)HID * 4096, 0, (size_t)(NO_PAD - HID) * 4096 * 2, stream);

  // mode-0: M=8192 (32 by), N=5120 (20 bx), K=2880 (NT=45); 640 blocks = 8 xcd x 5 rects
  gemm256<0><<<dim3(640), 512, 0, stream>>>(
      A_h, BTqkv, qkv, HID, 45, QKV_N - 1, 5, 5, bq, bk, bv);
  rope_kernel<<<73728, 256, 0, stream>>>(qkv, positions);
  attn_kernel<<<dim3(S_TOK / 64, NQ), 256, 0, stream>>>(qkv, attn);
  // mode-1: N=2944 (12 bx), K=4096 (NT=64); 384 blocks = 8 xcd x 3 rects
  gemm256<1><<<dim3(384), 512, 0, stream>>>(
      attn, BTo, out, 4096, 64, NO_PAD - 1, 3, 3, bo, nullptr, nullptr);
}

// Round 6
// 907.509 us; speedup vs baseline: 1.0297x; 1.0187x over previous
//
#include <hip/hip_runtime.h>
#include <stdint.h>

#define S_TOK 8192
#define HID 2880
#define NQ 64
#define NKV 8
#define HD 64
#define QKV_N 5120   // 4096 q + 512 k + 512 v
#define NO_PAD 2944  // 2880 padded to multiple of 128

typedef __attribute__((ext_vector_type(8))) __bf16 bf16x8;
typedef __attribute__((ext_vector_type(4))) float f32x4;

__device__ __forceinline__ unsigned short f2bf(float f) {
  unsigned int u = __builtin_bit_cast(unsigned int, f);
  u += 0x7fff + ((u >> 16) & 1);
  return (unsigned short)(u >> 16);
}
__device__ __forceinline__ float bf2f(unsigned short h) {
  unsigned int u = ((unsigned int)h) << 16;
  return __builtin_bit_cast(float, u);
}

__device__ __forceinline__ void async_lds16(const void* g, void* l) {
  __builtin_amdgcn_global_load_lds(
      (const __attribute__((address_space(1))) unsigned int*)g,
      (__attribute__((address_space(3))) unsigned int*)l, 16, 0, 0);
}

__device__ __forceinline__ void wg_barrier() {
  asm volatile("" ::: "memory");
  __builtin_amdgcn_s_barrier();
  asm volatile("" ::: "memory");
}

#define VMCNT(n) asm volatile("s_waitcnt vmcnt(" #n ")" ::: "memory")
#define LGKM0                                            \
  do {                                                   \
    asm volatile("s_waitcnt lgkmcnt(0)" ::: "memory");   \
    __builtin_amdgcn_sched_barrier(0);                   \
  } while (0)

// ---------------- elementwise f32 -> bf16 ----------------
__global__ __launch_bounds__(256) void cvt_bf16_kernel(
    const float* __restrict__ src, unsigned short* __restrict__ dst) {
  size_t i = ((size_t)blockIdx.x * 256 + threadIdx.x) * 8;
  float4 a = *(const float4*)(src + i);
  float4 b = *(const float4*)(src + i + 4);
  union { unsigned short u[8]; uint4 v; } o;
  o.u[0] = f2bf(a.x); o.u[1] = f2bf(a.y); o.u[2] = f2bf(a.z); o.u[3] = f2bf(a.w);
  o.u[4] = f2bf(b.x); o.u[5] = f2bf(b.y); o.u[6] = f2bf(b.z); o.u[7] = f2bf(b.w);
  *(uint4*)(dst + i) = o.v;
}

// ------------- transpose + convert: src[R][C] f32 -> dst[(c+rowOff)][R] bf16 -------------
__global__ __launch_bounds__(256) void transpose_cvt(
    const float* __restrict__ src, unsigned short* __restrict__ dst,
    int R, int C, int rowOff) {
  __shared__ float tile[32][33];
  int tx = threadIdx.x, ty = threadIdx.y;  // block (32,8)
  int c0 = blockIdx.x * 32, r0 = blockIdx.y * 32;
#pragma unroll
  for (int i = 0; i < 4; ++i)
    tile[ty + i * 8][tx] = src[(size_t)(r0 + ty + i * 8) * C + c0 + tx];
  __syncthreads();
#pragma unroll
  for (int i = 0; i < 4; ++i)
    dst[(size_t)(c0 + ty + i * 8 + rowOff) * R + r0 + tx] = f2bf(tile[tx][ty + i * 8]);
}

// ---------------- in-place RoPE on q (heads 0..63) and k (heads 64..71) ----------------
__global__ __launch_bounds__(256) void rope_kernel(
    unsigned short* __restrict__ qkv, const int* __restrict__ positions) {
  int gid = blockIdx.x * 256 + threadIdx.x;   // 8192*72*32 total
  int d = gid & 31;
  int rest = gid >> 5;
  int head = rest % 72;
  int t = rest / 72;
  unsigned short* p = qkv + (size_t)t * QKV_N + head * 64;
  float x1 = bf2f(p[d]);
  float x2 = bf2f(p[d + 32]);
  float pos = (float)positions[t];
  float inv = exp2f(-0.5373313430f * (float)d);
  float ang = pos * inv;
  float s = sinf(ang), c = cosf(ang);
  p[d] = f2bf(x1 * c - x2 * s);
  p[d + 32] = f2bf(x2 * c + x1 * s);
}

// ======================= 256x256 bf16 GEMM, m201-literal phases =======================
// Geometry/ledger/epilogue = round-5 kernel. CHANGED (round-5 post-mortem): phase order
// was {barrier; reads; lgkm0; MFMA} -- ds_read latency (~120cy) serial in all 180 phases
// and no wave de-phasing (MfmaUtil 34%). Now m201-literal:
//   { reads(own); stage; [vmcnt gate]; barrier; lgkmcnt(0); setprio+MFMA; barrier }
// Reads issue BEFORE the barrier (latency hides under join); double barrier lets waves
// de-phase so one wave's ds_reads overlap another's MFMA (m201: 62% MfmaUtil, same geom).
// WAR safety: every wave lgkm-drains its reads before the phase-end barrier, so stages
// in later phases cannot overwrite unread data.
// vmcnt ledger (unit = 1 stage = 2 loads; stages p0:A_k1(t+1), p1:B_k0(t+2),
// p2:A_k0(t+2), p3:B_k1(t+2)):
//   p1-tail gate guards p2 reads (B_k1(t),A_k1(t)): 5 newer units -> VMCNT(10)
//     tail: t==NT-2 -> 8, t==NT-1 -> 0.
//   p3-tail gate guards next-tile p0 reads (B_k0,A_k0): 5 newer units -> VMCNT(10)
//     tail: t==NT-2 -> 4, t==NT-1 -> skip.
// Never drains mid-loop (T4).
template <int MODE>
__global__ __launch_bounds__(512, 2) void gemm256(
    const unsigned short* __restrict__ A, const unsigned short* __restrict__ BT,
    void* __restrict__ Cout, int K, int NT, int nbClamp, int RPX, int RCOLS,
    const float* __restrict__ b0, const float* __restrict__ b1,
    const float* __restrict__ b2) {
  __shared__ unsigned short lds[65536];  // 128 KB
  const int tid = threadIdx.x;
  const int lane = tid & 63;
  const int wid = tid >> 6;
  const int wy = wid >> 2, wx = wid & 3;       // 2M x 4N wave grid
  const int l15 = lane & 15, l4 = lane >> 4;
  const int psw = l4 ^ ((l15 >> 1) & 3);       // thread-constant read swizzle chunk

  // XCD 4x4 cluster mapping (bijective: (xcd,s) -> (r,w) -> (by,bx))
  const int bid = blockIdx.x;
  const int xcd = bid & 7, s = bid >> 3;
  const int r = xcd * RPX + (s >> 4);
  const int w = s & 15;
  const int by = (r / RCOLS) * 4 + (w >> 2);
  const int bx = (r % RCOLS) * 4 + (w & 3);
  const int m0 = by * 256, n0 = bx * 256;

  const unsigned short* Ag = A + (size_t)m0 * K;

  // staging: thread-constant source chunk + row
  const int row0 = tid >> 2;
  const int gsw = (tid & 3) ^ ((tid >> 3) & 3);

  auto stageA = [&](int t, int kh, int buf) {
    const unsigned short* G = Ag + t * 64 + kh * 32;
    unsigned short* D = &lds[buf * 32768 + kh * 8192];
#pragma unroll
    for (int rd = 0; rd < 2; ++rd) {
      int row = row0 + rd * 128;
      async_lds16(G + (size_t)row * K + gsw * 8, D + (tid + rd * 512) * 8);
    }
  };
  auto stageB = [&](int t, int kh, int buf) {
    int koff = t * 64 + kh * 32;
    unsigned short* D = &lds[buf * 32768 + 16384 + kh * 8192];
#pragma unroll
    for (int rd = 0; rd < 2; ++rd) {
      int gr = n0 + row0 + rd * 128;
      gr = gr > nbClamp ? nbClamp : gr;
      async_lds16(BT + (size_t)gr * K + koff + gsw * 8, D + (tid + rd * 512) * 8);
    }
  };

  f32x4 acc[8][4];
#pragma unroll
  for (int m = 0; m < 8; ++m)
#pragma unroll
    for (int n = 0; n < 4; ++n)
#pragma unroll
      for (int r2 = 0; r2 < 4; ++r2) acc[m][n][r2] = 0.f;

  // prologue: 7 units in flight; gate B_k0(0)/A_k0(0) (5 newer units -> 10)
  stageB(0, 0, 0); stageA(0, 0, 0); stageB(0, 1, 0); stageA(0, 1, 0);
  stageB(1, 0, 1); stageA(1, 0, 1); stageB(1, 1, 1);
  VMCNT(10);
  wg_barrier();

  bf16x8 aq[4], bq[4];
  for (int t = 0; t < NT; ++t) {
    const int cur = t & 1;
    const unsigned short* Ab0 = &lds[cur * 32768];
    const unsigned short* Bb0 = Ab0 + 16384;
    const unsigned short* Ab1 = Ab0 + 8192;
    const unsigned short* Bb1 = Bb0 + 8192;

    // ---- p0: ks0, mh0 ----
#pragma unroll
    for (int n = 0; n < 4; ++n)
      bq[n] = *(const bf16x8*)&Bb0[(wx * 64 + n * 16 + l15) * 32 + psw * 8];
#pragma unroll
    for (int mi = 0; mi < 4; ++mi)
      aq[mi] = *(const bf16x8*)&Ab0[(wy * 128 + mi * 16 + l15) * 32 + psw * 8];
    if (t + 1 < NT) stageA(t + 1, 1, cur ^ 1);
    wg_barrier();
    LGKM0;
    __builtin_amdgcn_s_setprio(1);
#pragma unroll
    for (int mi = 0; mi < 4; ++mi)
#pragma unroll
      for (int n = 0; n < 4; ++n)
        acc[mi][n] = __builtin_amdgcn_mfma_f32_16x16x32_bf16(
            aq[mi], bq[n], acc[mi][n], 0, 0, 0);
    __builtin_amdgcn_s_setprio(0);
    wg_barrier();

    // ---- p1: ks0, mh1 (bq = B_k0 persists) ----
#pragma unroll
    for (int mi = 0; mi < 4; ++mi)
      aq[mi] = *(const bf16x8*)&Ab0[(wy * 128 + (mi + 4) * 16 + l15) * 32 + psw * 8];
    if (t + 2 < NT) stageB(t + 2, 0, cur);
    if (t + 2 < NT) { VMCNT(10); }
    else if (t + 1 < NT) { VMCNT(8); }
    else { VMCNT(0); }
    wg_barrier();
    LGKM0;
    __builtin_amdgcn_s_setprio(1);
#pragma unroll
    for (int mi = 0; mi < 4; ++mi)
#pragma unroll
      for (int n = 0; n < 4; ++n)
        acc[mi + 4][n] = __builtin_amdgcn_mfma_f32_16x16x32_bf16(
            aq[mi], bq[n], acc[mi + 4][n], 0, 0, 0);
    __builtin_amdgcn_s_setprio(0);
    wg_barrier();

    // ---- p2: ks1, mh0 ----
#pragma unroll
    for (int n = 0; n < 4; ++n)
      bq[n] = *(const bf16x8*)&Bb1[(wx * 64 + n * 16 + l15) * 32 + psw * 8];
#pragma unroll
    for (int mi = 0; mi < 4; ++mi)
      aq[mi] = *(const bf16x8*)&Ab1[(wy * 128 + mi * 16 + l15) * 32 + psw * 8];
    if (t + 2 < NT) stageA(t + 2, 0, cur);
    wg_barrier();
    LGKM0;
    __builtin_amdgcn_s_setprio(1);
#pragma unroll
    for (int mi = 0; mi < 4; ++mi)
#pragma unroll
      for (int n = 0; n < 4; ++n)
        acc[mi][n] = __builtin_amdgcn_mfma_f32_16x16x32_bf16(
            aq[mi], bq[n], acc[mi][n], 0, 0, 0);
    __builtin_amdgcn_s_setprio(0);
    wg_barrier();

    // ---- p3: ks1, mh1 (bq = B_k1 persists) ----
#pragma unroll
    for (int mi = 0; mi < 4; ++mi)
      aq[mi] = *(const bf16x8*)&Ab1[(wy * 128 + (mi + 4) * 16 + l15) * 32 + psw * 8];
    if (t + 2 < NT) stageB(t + 2, 1, cur);
    if (t + 2 < NT) { VMCNT(10); }
    else if (t + 1 < NT) { VMCNT(4); }
    wg_barrier();
    LGKM0;
    __builtin_amdgcn_s_setprio(1);
#pragma unroll
    for (int mi = 0; mi < 4; ++mi)
#pragma unroll
      for (int n = 0; n < 4; ++n)
        acc[mi + 4][n] = __builtin_amdgcn_mfma_f32_16x16x32_bf16(
            aq[mi], bq[n], acc[mi + 4][n], 0, 0, 0);
    __builtin_amdgcn_s_setprio(0);
    wg_barrier();
  }
  __syncthreads();

  // C/D layout (16x16): col = lane&15, row = (lane>>4)*4 + reg
  if (MODE == 0) {
    unsigned short* C16 = (unsigned short*)Cout;
    unsigned short* ldsC = lds;  // 128 rows x 264 stride per half
#pragma unroll
    for (int h = 0; h < 2; ++h) {
      if (wy == h) {
#pragma unroll
        for (int n = 0; n < 4; ++n) {
          int col = wx * 64 + n * 16 + l15;
          int gcol = n0 + col;
          float bias = (gcol < 4096) ? b0[gcol]
                                     : (gcol < 4608 ? b1[gcol - 4096] : b2[gcol - 4608]);
#pragma unroll
          for (int m = 0; m < 8; ++m)
#pragma unroll
            for (int r2 = 0; r2 < 4; ++r2)
              ldsC[(m * 16 + l4 * 4 + r2) * 264 + col] = f2bf(acc[m][n][r2] + bias);
        }
      }
      __syncthreads();
#pragma unroll
      for (int it = 0; it < 8; ++it) {  // 128 x 256 = 8 * 512 * 8
        int s2 = tid + it * 512;
        int row = s2 >> 5, c8 = (s2 & 31) * 8;
        *(uint4*)(C16 + (size_t)(m0 + h * 128 + row) * QKV_N + n0 + c8) =
            *(const uint4*)&ldsC[row * 264 + c8];
      }
      if (h == 0) __syncthreads();
    }
  } else {
    float* Cf = (float*)Cout;
#pragma unroll
    for (int n = 0; n < 4; ++n) {
      int gcol = n0 + wx * 64 + n * 16 + l15;
      if (gcol < HID) {
        float bias = b0[gcol];
#pragma unroll
        for (int m = 0; m < 8; ++m)
#pragma unroll
          for (int r2 = 0; r2 < 4; ++r2) {
            int row = m0 + wy * 128 + m * 16 + l4 * 4 + r2;
            Cf[(size_t)row * HID + gcol] = acc[m][n][r2] + bias;
          }
      }
    }
  }
}

// ---------------- sliding-window GQA attention ----------------
// grid (128 q-blocks of 64 rows, 64 heads); block 256
__global__ __launch_bounds__(256) void attn_kernel(
    const unsigned short* __restrict__ qkv, unsigned short* __restrict__ attn) {
  __shared__ unsigned short Qs[64 * 72];    // q rows, stride 72 (pad)
  __shared__ unsigned short Ks[192 * 72];   // ctx keys, stride 72; reused as P[64*200]
  __shared__ unsigned short VTs[64 * 200];  // V transposed: [dim][key], stride 200

  const int tid = threadIdx.x;
  const int B = blockIdx.x;   // 64-row query block
  const int h = blockIdx.y;
  const int hk = h >> 3;
  const int wave = tid >> 6, lane = tid & 63;
  const int quad = lane >> 4, ml = lane & 15;

  // stage Q: 64 rows x 64 cols
#pragma unroll
  for (int it = 0; it < 2; ++it) {
    int s = tid + it * 256;
    int row = s >> 3, c = (s & 7) << 3;
    *(uint4*)&Qs[row * 72 + c] =
        *(const uint4*)(qkv + (size_t)(B * 64 + row) * QKV_N + h * 64 + c);
  }
  // stage K (natural) and V (transposed): 192 ctx rows
#pragma unroll
  for (int it = 0; it < 6; ++it) {
    int s = tid + it * 256;
    int j = s >> 3, c = (s & 7) << 3;
    int tk = B * 64 - 128 + j;
    uint4 kv = make_uint4(0, 0, 0, 0), vv = make_uint4(0, 0, 0, 0);
    if (tk >= 0) {
      kv = *(const uint4*)(qkv + (size_t)tk * QKV_N + 4096 + hk * 64 + c);
      vv = *(const uint4*)(qkv + (size_t)tk * QKV_N + 4608 + hk * 64 + c);
    }
    *(uint4*)&Ks[j * 72 + c] = kv;
    union { uint4 q; unsigned short u[8]; } vu;
    vu.q = vv;
#pragma unroll
    for (int e = 0; e < 8; ++e) VTs[(c + e) * 200 + j] = vu.u[e];
  }
  __syncthreads();

  // scores: wave handles q rows [wave*16, wave*16+16), all 192 ctx cols
  f32x4 zero = {0.f, 0.f, 0.f, 0.f};
  f32x4 sc[12];
#pragma unroll
  for (int jn = 0; jn < 12; ++jn) sc[jn] = zero;
#pragma unroll
  for (int kk = 0; kk < 2; ++kk) {
    bf16x8 af = *(const bf16x8*)&Qs[(wave * 16 + ml) * 72 + kk * 32 + quad * 8];
#pragma unroll
    for (int jn = 0; jn < 12; ++jn) {
      bf16x8 bfr = *(const bf16x8*)&Ks[(jn * 16 + ml) * 72 + kk * 32 + quad * 8];
      sc[jn] = __builtin_amdgcn_mfma_f32_16x16x32_bf16(af, bfr, sc[jn], 0, 0, 0);
    }
  }

  // mask + scale + softmax (rows = wave*16 + quad*4 + r; col = jn*16 + ml)
  const float NEG = -3.0e38f;
  float mx[4], sm[4];
#pragma unroll
  for (int r = 0; r < 4; ++r) mx[r] = NEG;
#pragma unroll
  for (int jn = 0; jn < 12; ++jn) {
    int j = jn * 16 + ml;
#pragma unroll
    for (int r = 0; r < 4; ++r) {
      int i = wave * 16 + quad * 4 + r;
      bool valid = (j > i) && (j <= i + 128) && (B * 64 + j - 128 >= 0);
      float v = valid ? sc[jn][r] * 0.125f : NEG;
      sc[jn][r] = v;
      mx[r] = fmaxf(mx[r], v);
    }
  }
#pragma unroll
  for (int r = 0; r < 4; ++r) {
#pragma unroll
    for (int off = 1; off < 16; off <<= 1)
      mx[r] = fmaxf(mx[r], __shfl_xor(mx[r], off, 64));
    sm[r] = 0.f;
  }
#pragma unroll
  for (int jn = 0; jn < 12; ++jn) {
#pragma unroll
    for (int r = 0; r < 4; ++r) {
      float p = expf(sc[jn][r] - mx[r]);  // masked entries underflow to 0
      sc[jn][r] = p;
      sm[r] += p;
    }
  }
#pragma unroll
  for (int r = 0; r < 4; ++r) {
#pragma unroll
    for (int off = 1; off < 16; off <<= 1) sm[r] += __shfl_xor(sm[r], off, 64);
    sm[r] = 1.0f / sm[r];
  }
  __syncthreads();  // everyone done reading Qs/Ks before P overwrites Ks

  unsigned short* P = Ks;  // overlay: 64 rows, stride 200
#pragma unroll
  for (int jn = 0; jn < 12; ++jn) {
#pragma unroll
    for (int r = 0; r < 4; ++r)
      P[(wave * 16 + quad * 4 + r) * 200 + jn * 16 + ml] = f2bf(sc[jn][r] * sm[r]);
  }
  __syncthreads();

  // PV: O[16 x 64] per wave, K-dim = 192
  f32x4 ov[4];
#pragma unroll
  for (int jn = 0; jn < 4; ++jn) ov[jn] = zero;
#pragma unroll
  for (int ks = 0; ks < 6; ++ks) {
    bf16x8 af = *(const bf16x8*)&P[(wave * 16 + ml) * 200 + ks * 32 + quad * 8];
#pragma unroll
    for (int jn = 0; jn < 4; ++jn) {
      bf16x8 bfr = *(const bf16x8*)&VTs[(jn * 16 + ml) * 200 + ks * 32 + quad * 8];
      ov[jn] = __builtin_amdgcn_mfma_f32_16x16x32_bf16(af, bfr, ov[jn], 0, 0, 0);
    }
  }
#pragma unroll
  for (int jn = 0; jn < 4; ++jn) {
#pragma unroll
    for (int r = 0; r < 4; ++r) {
      int row = B * 64 + wave * 16 + quad * 4 + r;
      attn[(size_t)row * 4096 + h * 64 + jn * 16 + ml] = f2bf(ov[jn][r]);
    }
  }
}

extern "C" void kernel_launch(void* const* d_in, const int* in_sizes, int n_in,
                              void* d_out, int out_size, void* d_ws, size_t ws_size,
                              hipStream_t stream) {
  const float* hidden = (const float*)d_in[0];
  const int* positions = (const int*)d_in[1];
  const float* Wq = (const float*)d_in[2];
  const float* bq = (const float*)d_in[3];
  const float* Wk = (const float*)d_in[4];
  const float* bk = (const float*)d_in[5];
  const float* Wv = (const float*)d_in[6];
  const float* bv = (const float*)d_in[7];
  const float* Wo = (const float*)d_in[8];
  const float* bo = (const float*)d_in[9];
  float* out = (float*)d_out;

  char* ws = (char*)d_ws;
  unsigned short* A_h   = (unsigned short*)(ws);
  unsigned short* BTqkv = (unsigned short*)(ws + 47185920);
  unsigned short* qkv   = (unsigned short*)(ws + 76677120);
  unsigned short* BTo   = (unsigned short*)(ws + 160563200);
  unsigned short* attn  = (unsigned short*)(ws);

  cvt_bf16_kernel<<<11520, 256, 0, stream>>>(hidden, A_h);
  dim3 tb(32, 8);
  transpose_cvt<<<dim3(128, 90), tb, 0, stream>>>(Wq, BTqkv, HID, 4096, 0);
  transpose_cvt<<<dim3(16, 90), tb, 0, stream>>>(Wk, BTqkv, HID, 512, 4096);
  transpose_cvt<<<dim3(16, 90), tb, 0, stream>>>(Wv, BTqkv, HID, 512, 4608);
  transpose_cvt<<<dim3(90, 128), tb, 0, stream>>>(Wo, BTo, 4096, HID, 0);
  hipMemsetAsync(BTo + (size_t)HID * 4096, 0, (size_t)(NO_PAD - HID) * 4096 * 2, stream);

  // mode-0: M=8192 (32 by), N=5120 (20 bx), K=2880 (NT=45); 640 blocks = 8 xcd x 5 rects
  gemm256<0><<<dim3(640), 512, 0, stream>>>(
      A_h, BTqkv, qkv, HID, 45, QKV_N - 1, 5, 5, bq, bk, bv);
  rope_kernel<<<73728, 256, 0, stream>>>(qkv, positions);
  attn_kernel<<<dim3(S_TOK / 64, NQ), 256, 0, stream>>>(qkv, attn);
  // mode-1: N=2944 (12 bx), K=4096 (NT=64); 384 blocks = 8 xcd x 3 rects
  gemm256<1><<<dim3(384), 512, 0, stream>>>(
      attn, BTo, out, 4096, 64, NO_PAD - 1, 3, 3, bo, nullptr, nullptr);
}